// Round 10
// baseline (257.296 us; speedup 1.0000x reference)
//
#include <hip/hip_runtime.h>
#include <math.h>

// Problem constants (fixed by setup_inputs)
#define NQRY 8192   // queries
#define DIM  256    // d
#define MS   4608   // memory slots m
#define NQE  16384  // Nq embeddings
#define NBLK 8      // m // (C-1) partitions -> 8 blocks of 576
#define PRROWS 576

typedef __attribute__((ext_vector_type(8))) short bf16x8;
typedef __attribute__((ext_vector_type(4))) float f32x4;

// ---- d_out scratch layout (float offsets). All scratch is dead before
// k_read_mfma overwrites the entire output buffer. (R3/R6-proven layout) ----
// q f32      [8192][256]   @ 0
// qh bf16    [8192][256]   @ 2,097,152
// ql bf16    [8192][256]   @ 3,145,728
// kh bf16    [4608][256]   @ 4,194,304
// kl bf16    [4608][256]   @ 4,784,128
// qu f32     [4608][256]   @ 5,373,952
// rowbest u64[8192]        @ 6,553,600
// colmax u32 [4608]        @ 6,569,984
// memr f32   [4608][256]   @ 6,574,592   (ends 7,754,240 < 67,108,864)
// ---- d_ws layout (bytes): ebT bf16 [2][16384][256] @ 0 (16 MB);
//      Gb bf16 [8][256][256] @ 16,777,216 (1 MB); sc f32[4] @ 17,825,792.

// Order-preserving float<->uint mapping for atomicMax on floats
__device__ __forceinline__ unsigned ordf(float f) {
  unsigned u = __float_as_uint(f);
  return (u & 0x80000000u) ? ~u : (u | 0x80000000u);
}
__device__ __forceinline__ float unordf(unsigned u) {
  unsigned b = (u & 0x80000000u) ? (u & 0x7FFFFFFFu) : ~u;
  return __uint_as_float(b);
}
// round-to-nearest-even f32 -> bf16 bits
__device__ __forceinline__ unsigned short bf16rn(float x) {
  unsigned u = __float_as_uint(x);
  unsigned r = u + 0x7FFFu + ((u >> 16) & 1u);
  return (unsigned short)(r >> 16);
}
// split: x = hi(bf16, trunc) + lo(bf16, RN); residual <= 2^-17 |x|
__device__ __forceinline__ void splitbf(float x, unsigned short& h, unsigned short& lo) {
  unsigned u = __float_as_uint(x);
  h = (unsigned short)(u >> 16);
  float hf = __uint_as_float(u & 0xFFFF0000u);
  lo = bf16rn(x - hf);
}

// K_prep: fused prep pipeline, role by blockIdx range (R7-proven):
// [0,8192) qnorm | [8192,12800) ksplit | [12800,16896) embt
// [16896,18069) zero qu+rowbest+colmax | 18069 scalars
#define PREP_NBLK 18070
#define ZERO_N4   300160
__global__ __launch_bounds__(256) void k_prep(
    const float* __restrict__ query, float* __restrict__ q,
    unsigned short* __restrict__ qh, unsigned short* __restrict__ ql,
    const float* __restrict__ keys,
    unsigned short* __restrict__ kh, unsigned short* __restrict__ kl,
    const float* __restrict__ embS, const float* __restrict__ embT,
    unsigned short* __restrict__ ebT,
    float4* __restrict__ zp,
    const int* __restrict__ labels, const float* __restrict__ cc,
    float* __restrict__ sc) {
  __shared__ float tile[64][33];
  int b = blockIdx.x, t = threadIdx.x;
  if (b < 8192) {
    // qnorm
    size_t idx = (size_t)b * DIM + t;
    float x = query[idx];
    float v = x * x;
    #pragma unroll
    for (int o = 32; o; o >>= 1) v += __shfl_down(v, o);
    float* s = &tile[0][0];
    if ((t & 63) == 0) s[t >> 6] = v;
    __syncthreads();
    float ss = (s[0] + s[1]) + (s[2] + s[3]);
    float qq = x / fmaxf(sqrtf(ss), 1e-12f);
    q[idx] = qq;
    unsigned short h, lo;
    splitbf(qq, h, lo);
    qh[idx] = h; ql[idx] = lo;
  } else if (b < 12800) {
    // ksplit
    size_t idx = (size_t)(b - 8192) * 256 + t;
    unsigned short h, lo;
    splitbf(keys[idx], h, lo);
    kh[idx] = h; kl[idx] = lo;
  } else if (b < 16896) {
    // embt: transpose+convert emb [k][n] f32 -> ebT [n][k] bf16
    int bb = b - 12800;
    int x = bb & 511, y = (bb >> 9) & 3, z = bb >> 11;
    const float* emb = z ? embT : embS;
    int n0 = x * 32, k0 = y * 64;
    int kl2 = t >> 5, nl = t & 31;
    #pragma unroll
    for (int i = 0; i < 8; i++)
      tile[kl2 * 8 + i][nl] = emb[(size_t)(k0 + kl2 * 8 + i) * NQE + n0 + nl];
    __syncthreads();
    int nl2 = t >> 3, kq = (t & 7) * 8;
    bf16x8 hv;
    #pragma unroll
    for (int j = 0; j < 8; j++) hv[j] = (short)bf16rn(tile[kq + j][nl2]);
    *(bf16x8*)(ebT + (size_t)z * NQE * DIM + (size_t)(n0 + nl2) * DIM + k0 + kq) = hv;
  } else if (b < 18069) {
    // zero
    int i = (b - 16896) * 256 + t;
    if (i < ZERO_N4) zp[i] = float4{0.f, 0.f, 0.f, 0.f};
  } else {
    // scalars (wave 0 only)
    if (t < 64) {
      int l = (t < 16) ? labels[t] : (int)0x80000000;
      int mx = l;
      #pragma unroll
      for (int o = 32; o; o >>= 1) mx = max(mx, __shfl_down(mx, o));
      mx = __shfl(mx, 0);
      int cnt = (t < 16 && l == mx) ? 1 : 0;
      #pragma unroll
      for (int o = 32; o; o >>= 1) cnt += __shfl_down(cnt, o);
      unsigned amv = (t < 16) ? (1u << l) : 0u;
      #pragma unroll
      for (int o = 32; o; o >>= 1) amv |= __shfl_down(amv, o);
      if (t == 0) {
        sc[0] = __int_as_float(mx);
        sc[1] = (float)cnt;
        sc[2] = cc[mx];
        sc[3] = __uint_as_float(amv);
      }
    }
  }
}

// K4: score GEMM — R8 2-barrier template with A DIRECT FROM GLOBAL:
// the 16x16x32 A-fragment (8 contiguous bf16 at row m0+wm*64+f*16+lc,
// k = kk*32+lr*8) is one 16B global load from qh/ql (L2-resident panel,
// 36 consecutive blocks share it). LDS holds only B (16KB, kh/kl
// hi/lo-interleaved 128B rows, XOR swizzle, reg-prefetch). LDS ops per
// thread per K-step: 24 -> 12. Same epilogue, same numerics as R8.
__global__ __launch_bounds__(256) void k_scoremax(
    const unsigned short* __restrict__ qh, const unsigned short* __restrict__ ql,
    const unsigned short* __restrict__ kh, const unsigned short* __restrict__ kl,
    unsigned long long* __restrict__ rowbest, unsigned* __restrict__ colmax) {
  __shared__ __align__(16) char sB[16384];
  int tid = threadIdx.x;
  int n0 = blockIdx.x * 128, m0 = blockIdx.y * 128;   // n: slots, m: queries
  int w = tid >> 6, lane = tid & 63;
  int wm = w >> 1, wn = w & 1;
  int lr = lane >> 4, lc = lane & 15;
  int srow = tid >> 3, sc8 = tid & 7;   // staging: row-slot 0..31, chunk 0..7
  // B prefetch registers (4 x 16B per thread covers the 16KB B tile)
  bf16x8 pf[4];
  #pragma unroll
  for (int t = 0; t < 4; t++) {
    int row = t * 32 + srow;
    pf[t] = *(const bf16x8*)(((sc8 < 4) ? kh : kl) +
                             (size_t)(n0 + row) * DIM + (sc8 & 3) * 8);
  }
  // A fragment base pointers (per-lane row fixed across the K loop)
  const unsigned short* ah_base[4];
  const unsigned short* al_base[4];
  #pragma unroll
  for (int f = 0; f < 4; f++) {
    size_t ro = (size_t)(m0 + wm * 64 + f * 16 + lc) * DIM + lr * 8;
    ah_base[f] = qh + ro;
    al_base[f] = ql + ro;
  }
  f32x4 acc[4][4] = {};
  for (int kk = 0; kk < 8; kk++) {
    __syncthreads();   // previous compute done reading sB
    #pragma unroll
    for (int t = 0; t < 4; t++) {
      int row = t * 32 + srow;
      *(bf16x8*)(sB + row * 128 + ((sc8 ^ (row & 7)) << 4)) = pf[t];
    }
    __syncthreads();
    // A fragments straight from global (L2-hit panel)
    bf16x8 ah[4], al[4];
    #pragma unroll
    for (int f = 0; f < 4; f++) {
      ah[f] = *(const bf16x8*)(ah_base[f] + kk * 32);
      al[f] = *(const bf16x8*)(al_base[f] + kk * 32);
    }
    if (kk < 7) {      // prefetch next B K-tile (wave-uniform branch)
      #pragma unroll
      for (int t = 0; t < 4; t++) {
        int row = t * 32 + srow;
        pf[t] = *(const bf16x8*)(((sc8 < 4) ? kh : kl) +
                                 (size_t)(n0 + row) * DIM + (kk + 1) * 32 + (sc8 & 3) * 8);
      }
    }
    // B fragments in halves to cap live VGPRs
    #pragma unroll
    for (int half = 0; half < 2; half++) {
      bf16x8 bh[2], bl[2];
      #pragma unroll
      for (int f2 = 0; f2 < 2; f2++) {
        int rb = wn * 64 + (half * 2 + f2) * 16 + lc;
        bh[f2] = *(const bf16x8*)(sB + rb * 128 + ((lr ^ (rb & 7)) << 4));
        bl[f2] = *(const bf16x8*)(sB + rb * 128 + (((lr + 4) ^ (rb & 7)) << 4));
      }
      #pragma unroll
      for (int fm = 0; fm < 4; fm++)
        #pragma unroll
        for (int f2 = 0; f2 < 2; f2++) {
          int fn = half * 2 + f2;
          acc[fm][fn] = __builtin_amdgcn_mfma_f32_16x16x32_bf16(ah[fm], bh[f2], acc[fm][fn], 0, 0, 0);
          acc[fm][fn] = __builtin_amdgcn_mfma_f32_16x16x32_bf16(ah[fm], bl[f2], acc[fm][fn], 0, 0, 0);
          acc[fm][fn] = __builtin_amdgcn_mfma_f32_16x16x32_bf16(al[fm], bh[f2], acc[fm][fn], 0, 0, 0);
        }
    }
  }
  // epilogue: row argmax (packed u64) + column max (proven r2/r3/r6 form)
  #pragma unroll
  for (int fm = 0; fm < 4; fm++) {
    #pragma unroll
    for (int rg = 0; rg < 4; rg++) {
      unsigned long long p = 0ull;
      #pragma unroll
      for (int fn = 0; fn < 4; fn++) {
        float v = acc[fm][fn][rg];
        unsigned ng = (unsigned)(n0 + wn * 64 + fn * 16 + lc);
        unsigned long long cand =
            ((unsigned long long)ordf(v) << 32) | (unsigned long long)(0xFFFFFFFFu - ng);
        if (cand > p) p = cand;
      }
      #pragma unroll
      for (int o = 1; o < 16; o <<= 1) {
        unsigned long long t2 = __shfl_xor(p, o);
        if (t2 > p) p = t2;
      }
      if (lc == 0)
        atomicMax(rowbest + (m0 + wm * 64 + fm * 16 + lr * 4 + rg), p);
    }
  }
  #pragma unroll
  for (int fn = 0; fn < 4; fn++) {
    float v = -3.4e38f;
    #pragma unroll
    for (int fm = 0; fm < 4; fm++)
      #pragma unroll
      for (int rg = 0; rg < 4; rg++) v = fmaxf(v, acc[fm][fn][rg]);
    v = fmaxf(v, __shfl_xor(v, 16));
    v = fmaxf(v, __shfl_xor(v, 32));
    if (lr == 0) atomicMax(colmax + (n0 + wn * 64 + fn * 16 + lc), ordf(v));
  }
}

// K5: per-query scatter using rowbest/colmax only (no S).
__global__ __launch_bounds__(256) void k_rowscatter(
    const unsigned long long* __restrict__ rowbest, const unsigned* __restrict__ colmax,
    const float* __restrict__ q, float* __restrict__ qu) {
  int i = blockIdx.x, t = threadIdx.x;
  unsigned long long p = rowbest[i];
  int g = (int)(0xFFFFFFFFu - (unsigned)(p & 0xFFFFFFFFull));
  float sv = unordf((unsigned)(p >> 32));
  float w = expf(sv - unordf(colmax[g]));
  atomicAdd(qu + (size_t)g * DIM + t, w * q[(size_t)i * DIM + t]);
}

// K6: mem = l2norm((temp*keys + qu*active) / temp2)
__global__ __launch_bounds__(256) void k_mem(const float* __restrict__ keys,
                                             const float* __restrict__ qu,
                                             const float* __restrict__ sc,
                                             float* __restrict__ memr) {
  int j = blockIdx.x, t = threadIdx.x;
  int last = __float_as_int(sc[0]);
  float count = sc[1], ccl = sc[2];
  unsigned am = __float_as_uint(sc[3]);
  int cls = j >> 9;  // part = 512
  bool inp = (cls == last);
  float temp = inp ? ccl : 1.0f;
  float quv = ((am >> cls) & 1u) ? qu[(size_t)j * DIM + t] : 0.0f;
  float u = temp * keys[(size_t)j * DIM + t] + quv;
  float temp2 = temp + (inp ? count : 0.0f);
  float v = u / temp2;
  float vv = v * v;
  #pragma unroll
  for (int o = 32; o; o >>= 1) vv += __shfl_down(vv, o);
  __shared__ float s[4];
  if ((t & 63) == 0) s[t >> 6] = vv;
  __syncthreads();
  float ss = (s[0] + s[1]) + (s[2] + s[3]);
  memr[(size_t)j * DIM + t] = v / fmaxf(sqrtf(ss), 1e-12f);
}

// K7: G_b = B_b^T B_b (f32 vector compute), emit single bf16 (RN).
__global__ __launch_bounds__(256) void k_gram(const float* __restrict__ memr,
                                              unsigned short* __restrict__ Gb) {
  __shared__ float As[16][64];
  __shared__ float Bs[16][64];
  int b = blockIdx.z;
  int kxc = blockIdx.x * 64;
  int kyr = blockIdx.y * 64;
  const float* Ab = memr + (size_t)b * PRROWS * DIM;
  int tid = threadIdx.x, tx = tid & 15, ty = tid >> 4;
  int lp = tid >> 4;
  int lk = (tid & 15) * 4;
  float acc[4][4] = {};
  for (int p0 = 0; p0 < PRROWS; p0 += 16) {
    float4 av = *(const float4*)(Ab + (size_t)(p0 + lp) * DIM + kyr + lk);
    float4 bv = *(const float4*)(Ab + (size_t)(p0 + lp) * DIM + kxc + lk);
    __syncthreads();
    *(float4*)&As[lp][lk] = av;
    *(float4*)&Bs[lp][lk] = bv;
    __syncthreads();
    #pragma unroll
    for (int p = 0; p < 16; p++) {
      float a[4], c[4];
      *(float4*)&a[0] = *(const float4*)&As[p][ty * 4];
      *(float4*)&c[0] = *(const float4*)&Bs[p][tx * 4];
      #pragma unroll
      for (int r = 0; r < 4; r++)
        #pragma unroll
        for (int s2 = 0; s2 < 4; s2++)
          acc[r][s2] = fmaf(a[r], c[s2], acc[r][s2]);
    }
  }
  #pragma unroll
  for (int r = 0; r < 4; r++)
    #pragma unroll
    for (int s2 = 0; s2 < 4; s2++)
      Gb[(size_t)b * DIM * DIM + (size_t)(kyr + ty * 4 + r) * DIM + kxc + tx * 4 + s2] =
          bf16rn(acc[r][s2]);
}

// K8: out[eb][n][d] = ebT_e[n,:] @ G_b, 1-pass bf16 MFMA, reg-staged LDS
// (verbatim round-3/6 kernel: validated + replay-stable).
__global__ __launch_bounds__(256) void k_read_mfma(
    const unsigned short* __restrict__ ebT, const unsigned short* __restrict__ Gb,
    float* __restrict__ out) {
  __shared__ __align__(16) char smem[32768];
  char* sA = smem;
  char* sB = smem + 16384;
  int tid = threadIdx.x;
  int eb = blockIdx.z;
  const unsigned short* ea = ebT + (size_t)(eb >> 3) * NQE * DIM;
  const unsigned short* gb = Gb + (size_t)(eb & 7) * DIM * DIM;
  int n0 = blockIdx.x * 128, d0 = blockIdx.y * 128;
  int w = tid >> 6, l = tid & 63;
  int wm = w >> 1, wn = w & 1;
  int lr = l >> 4, lc = l & 15;
  f32x4 acc[4][4] = {};
  for (int kk = 0; kk < 4; kk++) {
    __syncthreads();
    #pragma unroll
    for (int t = 0; t < 4; t++) {
      int c = t * 256 + tid;            // 16B chunk id, 0..1023
      int row = c >> 3, cc = c & 7;
      int ldsb = row * 128 + ((cc * 16) ^ ((row & 7) << 4));
      size_t gA = (size_t)(n0 + row) * DIM + kk * 64 + cc * 8;
      size_t gB = (size_t)(d0 + row) * DIM + kk * 64 + cc * 8;
      *(bf16x8*)(sA + ldsb) = *(const bf16x8*)(ea + gA);
      *(bf16x8*)(sB + ldsb) = *(const bf16x8*)(gb + gB);
    }
    __syncthreads();
    #pragma unroll
    for (int st = 0; st < 2; st++) {
      bf16x8 af[4], bf[4];
      #pragma unroll
      for (int f = 0; f < 4; f++) {
        int ra = wm * 64 + f * 16 + lc;
        int ka = (st * 64 + lr * 16) ^ ((ra & 7) << 4);
        af[f] = *(const bf16x8*)(sA + ra * 128 + ka);
        int rb = wn * 64 + f * 16 + lc;
        int kb = (st * 64 + lr * 16) ^ ((rb & 7) << 4);
        bf[f] = *(const bf16x8*)(sB + rb * 128 + kb);
      }
      #pragma unroll
      for (int fm = 0; fm < 4; fm++)
        #pragma unroll
        for (int fn = 0; fn < 4; fn++)
          acc[fm][fn] = __builtin_amdgcn_mfma_f32_16x16x32_bf16(af[fm], bf[fn], acc[fm][fn], 0, 0, 0);
    }
  }
  size_t base = (size_t)eb * NQE * DIM;
  #pragma unroll
  for (int fm = 0; fm < 4; fm++)
    #pragma unroll
    for (int rg = 0; rg < 4; rg++) {
      int n = n0 + wm * 64 + fm * 16 + lr * 4 + rg;
      float* op = out + base + (size_t)n * DIM + d0 + wn * 64 + lc;
      #pragma unroll
      for (int fn = 0; fn < 4; fn++) op[fn * 16] = acc[fm][fn][rg];
    }
}

extern "C" void kernel_launch(void* const* d_in, const int* in_sizes, int n_in,
                              void* d_out, int out_size, void* d_ws, size_t ws_size,
                              hipStream_t stream) {
  const float* query  = (const float*)d_in[0];
  const float* embS   = (const float*)d_in[1];
  const float* embT   = (const float*)d_in[2];
  const float* keys   = (const float*)d_in[3];
  const float* cc     = (const float*)d_in[4];
  const int*   labels = (const int*)d_in[5];
  float* out = (float*)d_out;

  float* q                     = out;
  unsigned short* qh           = (unsigned short*)(out + 2097152);
  unsigned short* ql           = (unsigned short*)(out + 3145728);
  unsigned short* kh           = (unsigned short*)(out + 4194304);
  unsigned short* kl           = (unsigned short*)(out + 4784128);
  float* qu                    = out + 5373952;
  unsigned long long* rowbest  = (unsigned long long*)(out + 6553600);
  unsigned* colmax             = (unsigned*)(out + 6569984);
  float* memr                  = out + 6574592;

  unsigned short* ebT = (unsigned short*)d_ws;                         // 16 MB
  unsigned short* Gb  = (unsigned short*)((char*)d_ws + 16777216);     // 1 MB
  float* sc           = (float*)((char*)d_ws + 17825792);              // 16 B

  k_prep<<<PREP_NBLK, 256, 0, stream>>>(query, q, qh, ql, keys, kh, kl,
                                        embS, embT, ebT, (float4*)qu,
                                        labels, cc, sc);
  k_scoremax<<<dim3(MS / 128, NQRY / 128), 256, 0, stream>>>(qh, ql, kh, kl, rowbest, colmax);
  k_rowscatter<<<NQRY, 256, 0, stream>>>(rowbest, colmax, q, qu);
  k_mem<<<MS, 256, 0, stream>>>(keys, qu, sc, memr);
  k_gram<<<dim3(4, 4, NBLK), 256, 0, stream>>>(memr, Gb);
  k_read_mfma<<<dim3(NQE / 128, DIM / 128, 2 * NBLK), 256, 0, stream>>>(ebT, Gb, out);
}

// Round 11
// 230.501 us; speedup vs baseline: 1.1162x; 1.1162x over previous
//
#include <hip/hip_runtime.h>
#include <math.h>

// Problem constants (fixed by setup_inputs)
#define NQRY 8192   // queries
#define DIM  256    // d
#define MS   4608   // memory slots m
#define NQE  16384  // Nq embeddings
#define NBLK 8      // m // (C-1) partitions -> 8 blocks of 576
#define PRROWS 576

typedef __attribute__((ext_vector_type(8))) short bf16x8;
typedef __attribute__((ext_vector_type(4))) float f32x4;

// ---- d_out scratch layout (float offsets). All scratch is dead before
// k_read_mfma overwrites the entire output buffer. (R3/R6-proven layout) ----
// q f32      [8192][256]   @ 0
// qh bf16    [8192][256]   @ 2,097,152
// ql bf16    [8192][256]   @ 3,145,728
// kh bf16    [4608][256]   @ 4,194,304
// kl bf16    [4608][256]   @ 4,784,128
// qu f32     [4608][256]   @ 5,373,952
// rowbest u64[8192]        @ 6,553,600
// colmax u32 [4608]        @ 6,569,984
// memr f32   [4608][256]   @ 6,574,592   (ends 7,754,240 < 67,108,864)
// ---- d_ws layout (bytes): ebT bf16 [2][16384][256] @ 0 (16 MB);
//      Gb bf16 [8][256][256] @ 16,777,216 (1 MB); sc f32[4] @ 17,825,792.

// async global->LDS, 16B/lane; LDS dest = wave-uniform base + lane*16
__device__ __forceinline__ void gl_lds16(const void* g, void* l) {
  __builtin_amdgcn_global_load_lds(
      (const __attribute__((address_space(1))) void*)g,
      (__attribute__((address_space(3))) void*)l, 16, 0, 0);
}

// Order-preserving float<->uint mapping for atomicMax on floats
__device__ __forceinline__ unsigned ordf(float f) {
  unsigned u = __float_as_uint(f);
  return (u & 0x80000000u) ? ~u : (u | 0x80000000u);
}
__device__ __forceinline__ float unordf(unsigned u) {
  unsigned b = (u & 0x80000000u) ? (u & 0x7FFFFFFFu) : ~u;
  return __uint_as_float(b);
}
// round-to-nearest-even f32 -> bf16 bits
__device__ __forceinline__ unsigned short bf16rn(float x) {
  unsigned u = __float_as_uint(x);
  unsigned r = u + 0x7FFFu + ((u >> 16) & 1u);
  return (unsigned short)(r >> 16);
}
// split: x = hi(bf16, trunc) + lo(bf16, RN); residual <= 2^-17 |x|
__device__ __forceinline__ void splitbf(float x, unsigned short& h, unsigned short& lo) {
  unsigned u = __float_as_uint(x);
  h = (unsigned short)(u >> 16);
  float hf = __uint_as_float(u & 0xFFFF0000u);
  lo = bf16rn(x - hf);
}

// K_prep: fused prep pipeline, role by blockIdx range (R7-proven):
// [0,8192) qnorm | [8192,12800) ksplit | [12800,16896) embt
// [16896,18069) zero qu+rowbest+colmax | 18069 scalars
#define PREP_NBLK 18070
#define ZERO_N4   300160
__global__ __launch_bounds__(256) void k_prep(
    const float* __restrict__ query, float* __restrict__ q,
    unsigned short* __restrict__ qh, unsigned short* __restrict__ ql,
    const float* __restrict__ keys,
    unsigned short* __restrict__ kh, unsigned short* __restrict__ kl,
    const float* __restrict__ embS, const float* __restrict__ embT,
    unsigned short* __restrict__ ebT,
    float4* __restrict__ zp,
    const int* __restrict__ labels, const float* __restrict__ cc,
    float* __restrict__ sc) {
  __shared__ float tile[64][33];
  int b = blockIdx.x, t = threadIdx.x;
  if (b < 8192) {
    // qnorm
    size_t idx = (size_t)b * DIM + t;
    float x = query[idx];
    float v = x * x;
    #pragma unroll
    for (int o = 32; o; o >>= 1) v += __shfl_down(v, o);
    float* s = &tile[0][0];
    if ((t & 63) == 0) s[t >> 6] = v;
    __syncthreads();
    float ss = (s[0] + s[1]) + (s[2] + s[3]);
    float qq = x / fmaxf(sqrtf(ss), 1e-12f);
    q[idx] = qq;
    unsigned short h, lo;
    splitbf(qq, h, lo);
    qh[idx] = h; ql[idx] = lo;
  } else if (b < 12800) {
    // ksplit
    size_t idx = (size_t)(b - 8192) * 256 + t;
    unsigned short h, lo;
    splitbf(keys[idx], h, lo);
    kh[idx] = h; kl[idx] = lo;
  } else if (b < 16896) {
    // embt: transpose+convert emb [k][n] f32 -> ebT [n][k] bf16
    int bb = b - 12800;
    int x = bb & 511, y = (bb >> 9) & 3, z = bb >> 11;
    const float* emb = z ? embT : embS;
    int n0 = x * 32, k0 = y * 64;
    int kl2 = t >> 5, nl = t & 31;
    #pragma unroll
    for (int i = 0; i < 8; i++)
      tile[kl2 * 8 + i][nl] = emb[(size_t)(k0 + kl2 * 8 + i) * NQE + n0 + nl];
    __syncthreads();
    int nl2 = t >> 3, kq = (t & 7) * 8;
    bf16x8 hv;
    #pragma unroll
    for (int j = 0; j < 8; j++) hv[j] = (short)bf16rn(tile[kq + j][nl2]);
    *(bf16x8*)(ebT + (size_t)z * NQE * DIM + (size_t)(n0 + nl2) * DIM + k0 + kq) = hv;
  } else if (b < 18069) {
    // zero
    int i = (b - 16896) * 256 + t;
    if (i < ZERO_N4) zp[i] = float4{0.f, 0.f, 0.f, 0.f};
  } else {
    // scalars (wave 0 only)
    if (t < 64) {
      int l = (t < 16) ? labels[t] : (int)0x80000000;
      int mx = l;
      #pragma unroll
      for (int o = 32; o; o >>= 1) mx = max(mx, __shfl_down(mx, o));
      mx = __shfl(mx, 0);
      int cnt = (t < 16 && l == mx) ? 1 : 0;
      #pragma unroll
      for (int o = 32; o; o >>= 1) cnt += __shfl_down(cnt, o);
      unsigned amv = (t < 16) ? (1u << l) : 0u;
      #pragma unroll
      for (int o = 32; o; o >>= 1) amv |= __shfl_down(amv, o);
      if (t == 0) {
        sc[0] = __int_as_float(mx);
        sc[1] = (float)cnt;
        sc[2] = cc[mx];
        sc[3] = __uint_as_float(amv);
      }
    }
  }
}

// K4: score GEMM — R8's proven geometry (16x16x32 MFMA, BK=32 hi/lo
// interleaved 128B rows, XOR-(row&7) swizzle, 32KB LDS, 2-barrier m97
// template) with global_load_lds width-16 staging (m97's +67% lever):
// linear LDS dest + inverse-swizzled per-lane global source; read path is
// byte-identical to R8 (same involution) -> identical numerics.
// sched_barrier(0) fences pin the gl_lds cluster strictly between the two
// __syncthreads() (R4-race hypothesis: compiler motion across the barrier).
__global__ __launch_bounds__(256) void k_scoremax(
    const unsigned short* __restrict__ qh, const unsigned short* __restrict__ ql,
    const unsigned short* __restrict__ kh, const unsigned short* __restrict__ kl,
    unsigned long long* __restrict__ rowbest, unsigned* __restrict__ colmax) {
  __shared__ __align__(16) char smem[32768];
  char* sA = smem;
  char* sB = smem + 16384;
  int tid = threadIdx.x;
  int n0 = blockIdx.x * 128, m0 = blockIdx.y * 128;   // n: slots, m: queries
  int w = tid >> 6, lane = tid & 63;
  int wm = w >> 1, wn = w & 1;
  int lr = lane >> 4, lc = lane & 15;
  f32x4 acc[4][4] = {};
  for (int kk = 0; kk < 8; kk++) {
    __builtin_amdgcn_sched_barrier(0);
    __syncthreads();   // previous compute done reading LDS
    __builtin_amdgcn_sched_barrier(0);
    #pragma unroll
    for (int i = 0; i < 4; i++) {
      int c = w * 256 + i * 64 + lane;   // 16B chunk id 0..1023
      int row = c >> 3, ch = c & 7;
      int lch = ch ^ (row & 7);          // logical chunk stored at this slot
      const unsigned short* srcA = ((lch < 4) ? qh : ql) +
          (size_t)(m0 + row) * DIM + kk * 32 + (lch & 3) * 8;
      const unsigned short* srcB = ((lch < 4) ? kh : kl) +
          (size_t)(n0 + row) * DIM + kk * 32 + (lch & 3) * 8;
      gl_lds16(srcA, sA + (w * 256 + i * 64) * 16);
      gl_lds16(srcB, sB + (w * 256 + i * 64) * 16);
    }
    __builtin_amdgcn_sched_barrier(0);
    __syncthreads();   // drains vmcnt(0): staged tile visible
    __builtin_amdgcn_sched_barrier(0);
    bf16x8 ah[4], al[4];
    #pragma unroll
    for (int f = 0; f < 4; f++) {
      int ra = wm * 64 + f * 16 + lc;
      ah[f] = *(const bf16x8*)(sA + ra * 128 + ((lr ^ (ra & 7)) << 4));
      al[f] = *(const bf16x8*)(sA + ra * 128 + (((lr + 4) ^ (ra & 7)) << 4));
    }
    // B fragments in halves to cap live VGPRs
    #pragma unroll
    for (int half = 0; half < 2; half++) {
      bf16x8 bh[2], bl[2];
      #pragma unroll
      for (int f2 = 0; f2 < 2; f2++) {
        int rb = wn * 64 + (half * 2 + f2) * 16 + lc;
        bh[f2] = *(const bf16x8*)(sB + rb * 128 + ((lr ^ (rb & 7)) << 4));
        bl[f2] = *(const bf16x8*)(sB + rb * 128 + (((lr + 4) ^ (rb & 7)) << 4));
      }
      #pragma unroll
      for (int fm = 0; fm < 4; fm++)
        #pragma unroll
        for (int f2 = 0; f2 < 2; f2++) {
          int fn = half * 2 + f2;
          acc[fm][fn] = __builtin_amdgcn_mfma_f32_16x16x32_bf16(ah[fm], bh[f2], acc[fm][fn], 0, 0, 0);
          acc[fm][fn] = __builtin_amdgcn_mfma_f32_16x16x32_bf16(ah[fm], bl[f2], acc[fm][fn], 0, 0, 0);
          acc[fm][fn] = __builtin_amdgcn_mfma_f32_16x16x32_bf16(al[fm], bh[f2], acc[fm][fn], 0, 0, 0);
        }
    }
  }
  // epilogue: row argmax (packed u64) + column max (proven r2/r3/r6 form)
  #pragma unroll
  for (int fm = 0; fm < 4; fm++) {
    #pragma unroll
    for (int rg = 0; rg < 4; rg++) {
      unsigned long long p = 0ull;
      #pragma unroll
      for (int fn = 0; fn < 4; fn++) {
        float v = acc[fm][fn][rg];
        unsigned ng = (unsigned)(n0 + wn * 64 + fn * 16 + lc);
        unsigned long long cand =
            ((unsigned long long)ordf(v) << 32) | (unsigned long long)(0xFFFFFFFFu - ng);
        if (cand > p) p = cand;
      }
      #pragma unroll
      for (int o = 1; o < 16; o <<= 1) {
        unsigned long long t2 = __shfl_xor(p, o);
        if (t2 > p) p = t2;
      }
      if (lc == 0)
        atomicMax(rowbest + (m0 + wm * 64 + fm * 16 + lr * 4 + rg), p);
    }
  }
  #pragma unroll
  for (int fn = 0; fn < 4; fn++) {
    float v = -3.4e38f;
    #pragma unroll
    for (int fm = 0; fm < 4; fm++)
      #pragma unroll
      for (int rg = 0; rg < 4; rg++) v = fmaxf(v, acc[fm][fn][rg]);
    v = fmaxf(v, __shfl_xor(v, 16));
    v = fmaxf(v, __shfl_xor(v, 32));
    if (lr == 0) atomicMax(colmax + (n0 + wn * 64 + fn * 16 + lc), ordf(v));
  }
}

// K5: per-query scatter using rowbest/colmax only (no S).
__global__ __launch_bounds__(256) void k_rowscatter(
    const unsigned long long* __restrict__ rowbest, const unsigned* __restrict__ colmax,
    const float* __restrict__ q, float* __restrict__ qu) {
  int i = blockIdx.x, t = threadIdx.x;
  unsigned long long p = rowbest[i];
  int g = (int)(0xFFFFFFFFu - (unsigned)(p & 0xFFFFFFFFull));
  float sv = unordf((unsigned)(p >> 32));
  float w = expf(sv - unordf(colmax[g]));
  atomicAdd(qu + (size_t)g * DIM + t, w * q[(size_t)i * DIM + t]);
}

// K6: mem = l2norm((temp*keys + qu*active) / temp2)
__global__ __launch_bounds__(256) void k_mem(const float* __restrict__ keys,
                                             const float* __restrict__ qu,
                                             const float* __restrict__ sc,
                                             float* __restrict__ memr) {
  int j = blockIdx.x, t = threadIdx.x;
  int last = __float_as_int(sc[0]);
  float count = sc[1], ccl = sc[2];
  unsigned am = __float_as_uint(sc[3]);
  int cls = j >> 9;  // part = 512
  bool inp = (cls == last);
  float temp = inp ? ccl : 1.0f;
  float quv = ((am >> cls) & 1u) ? qu[(size_t)j * DIM + t] : 0.0f;
  float u = temp * keys[(size_t)j * DIM + t] + quv;
  float temp2 = temp + (inp ? count : 0.0f);
  float v = u / temp2;
  float vv = v * v;
  #pragma unroll
  for (int o = 32; o; o >>= 1) vv += __shfl_down(vv, o);
  __shared__ float s[4];
  if ((t & 63) == 0) s[t >> 6] = vv;
  __syncthreads();
  float ss = (s[0] + s[1]) + (s[2] + s[3]);
  memr[(size_t)j * DIM + t] = v / fmaxf(sqrtf(ss), 1e-12f);
}

// K7: G_b = B_b^T B_b (f32 vector compute), emit single bf16 (RN).
__global__ __launch_bounds__(256) void k_gram(const float* __restrict__ memr,
                                              unsigned short* __restrict__ Gb) {
  __shared__ float As[16][64];
  __shared__ float Bs[16][64];
  int b = blockIdx.z;
  int kxc = blockIdx.x * 64;
  int kyr = blockIdx.y * 64;
  const float* Ab = memr + (size_t)b * PRROWS * DIM;
  int tid = threadIdx.x, tx = tid & 15, ty = tid >> 4;
  int lp = tid >> 4;
  int lk = (tid & 15) * 4;
  float acc[4][4] = {};
  for (int p0 = 0; p0 < PRROWS; p0 += 16) {
    float4 av = *(const float4*)(Ab + (size_t)(p0 + lp) * DIM + kyr + lk);
    float4 bv = *(const float4*)(Ab + (size_t)(p0 + lp) * DIM + kxc + lk);
    __syncthreads();
    *(float4*)&As[lp][lk] = av;
    *(float4*)&Bs[lp][lk] = bv;
    __syncthreads();
    #pragma unroll
    for (int p = 0; p < 16; p++) {
      float a[4], c[4];
      *(float4*)&a[0] = *(const float4*)&As[p][ty * 4];
      *(float4*)&c[0] = *(const float4*)&Bs[p][tx * 4];
      #pragma unroll
      for (int r = 0; r < 4; r++)
        #pragma unroll
        for (int s2 = 0; s2 < 4; s2++)
          acc[r][s2] = fmaf(a[r], c[s2], acc[r][s2]);
    }
  }
  #pragma unroll
  for (int r = 0; r < 4; r++)
    #pragma unroll
    for (int s2 = 0; s2 < 4; s2++)
      Gb[(size_t)b * DIM * DIM + (size_t)(kyr + ty * 4 + r) * DIM + kxc + tx * 4 + s2] =
          bf16rn(acc[r][s2]);
}

// K8: out[eb][n][d] = ebT_e[n,:] @ G_b, 1-pass bf16 MFMA, reg-staged LDS
// (verbatim round-3/6/8 kernel: validated + replay-stable).
__global__ __launch_bounds__(256) void k_read_mfma(
    const unsigned short* __restrict__ ebT, const unsigned short* __restrict__ Gb,
    float* __restrict__ out) {
  __shared__ __align__(16) char smem[32768];
  char* sA = smem;
  char* sB = smem + 16384;
  int tid = threadIdx.x;
  int eb = blockIdx.z;
  const unsigned short* ea = ebT + (size_t)(eb >> 3) * NQE * DIM;
  const unsigned short* gb = Gb + (size_t)(eb & 7) * DIM * DIM;
  int n0 = blockIdx.x * 128, d0 = blockIdx.y * 128;
  int w = tid >> 6, l = tid & 63;
  int wm = w >> 1, wn = w & 1;
  int lr = l >> 4, lc = l & 15;
  f32x4 acc[4][4] = {};
  for (int kk = 0; kk < 4; kk++) {
    __syncthreads();
    #pragma unroll
    for (int t = 0; t < 4; t++) {
      int c = t * 256 + tid;            // 16B chunk id, 0..1023
      int row = c >> 3, cc = c & 7;
      int ldsb = row * 128 + ((cc * 16) ^ ((row & 7) << 4));
      size_t gA = (size_t)(n0 + row) * DIM + kk * 64 + cc * 8;
      size_t gB = (size_t)(d0 + row) * DIM + kk * 64 + cc * 8;
      *(bf16x8*)(sA + ldsb) = *(const bf16x8*)(ea + gA);
      *(bf16x8*)(sB + ldsb) = *(const bf16x8*)(gb + gB);
    }
    __syncthreads();
    #pragma unroll
    for (int st = 0; st < 2; st++) {
      bf16x8 af[4], bf[4];
      #pragma unroll
      for (int f = 0; f < 4; f++) {
        int ra = wm * 64 + f * 16 + lc;
        int ka = (st * 64 + lr * 16) ^ ((ra & 7) << 4);
        af[f] = *(const bf16x8*)(sA + ra * 128 + ka);
        int rb = wn * 64 + f * 16 + lc;
        int kb = (st * 64 + lr * 16) ^ ((rb & 7) << 4);
        bf[f] = *(const bf16x8*)(sB + rb * 128 + kb);
      }
      #pragma unroll
      for (int fm = 0; fm < 4; fm++)
        #pragma unroll
        for (int fn = 0; fn < 4; fn++)
          acc[fm][fn] = __builtin_amdgcn_mfma_f32_16x16x32_bf16(af[fm], bf[fn], acc[fm][fn], 0, 0, 0);
    }
  }
  size_t base = (size_t)eb * NQE * DIM;
  #pragma unroll
  for (int fm = 0; fm < 4; fm++)
    #pragma unroll
    for (int rg = 0; rg < 4; rg++) {
      int n = n0 + wm * 64 + fm * 16 + lr * 4 + rg;
      float* op = out + base + (size_t)n * DIM + d0 + wn * 64 + lc;
      #pragma unroll
      for (int fn = 0; fn < 4; fn++) op[fn * 16] = acc[fm][fn][rg];
    }
}

extern "C" void kernel_launch(void* const* d_in, const int* in_sizes, int n_in,
                              void* d_out, int out_size, void* d_ws, size_t ws_size,
                              hipStream_t stream) {
  const float* query  = (const float*)d_in[0];
  const float* embS   = (const float*)d_in[1];
  const float* embT   = (const float*)d_in[2];
  const float* keys   = (const float*)d_in[3];
  const float* cc     = (const float*)d_in[4];
  const int*   labels = (const int*)d_in[5];
  float* out = (float*)d_out;

  float* q                     = out;
  unsigned short* qh           = (unsigned short*)(out + 2097152);
  unsigned short* ql           = (unsigned short*)(out + 3145728);
  unsigned short* kh           = (unsigned short*)(out + 4194304);
  unsigned short* kl           = (unsigned short*)(out + 4784128);
  float* qu                    = out + 5373952;
  unsigned long long* rowbest  = (unsigned long long*)(out + 6553600);
  unsigned* colmax             = (unsigned*)(out + 6569984);
  float* memr                  = out + 6574592;

  unsigned short* ebT = (unsigned short*)d_ws;                         // 16 MB
  unsigned short* Gb  = (unsigned short*)((char*)d_ws + 16777216);     // 1 MB
  float* sc           = (float*)((char*)d_ws + 17825792);              // 16 B

  k_prep<<<PREP_NBLK, 256, 0, stream>>>(query, q, qh, ql, keys, kh, kl,
                                        embS, embT, ebT, (float4*)qu,
                                        labels, cc, sc);
  k_scoremax<<<dim3(MS / 128, NQRY / 128), 256, 0, stream>>>(qh, ql, kh, kl, rowbest, colmax);
  k_rowscatter<<<NQRY, 256, 0, stream>>>(rowbest, colmax, q, qu);
  k_mem<<<MS, 256, 0, stream>>>(keys, qu, sc, memr);
  k_gram<<<dim3(4, 4, NBLK), 256, 0, stream>>>(memr, Gb);
  k_read_mfma<<<dim3(NQE / 128, DIM / 128, 2 * NBLK), 256, 0, stream>>>(ebT, Gb, out);
}

// Round 12
// 228.599 us; speedup vs baseline: 1.1255x; 1.0083x over previous
//
#include <hip/hip_runtime.h>
#include <math.h>

// Problem constants (fixed by setup_inputs)
#define NQRY 8192   // queries
#define DIM  256    // d
#define MS   4608   // memory slots m
#define NQE  16384  // Nq embeddings
#define NBLK 8      // m // (C-1) partitions -> 8 blocks of 576
#define PRROWS 576

typedef __attribute__((ext_vector_type(8))) short bf16x8;
typedef __attribute__((ext_vector_type(4))) float f32x4;

// ---- d_out scratch layout (float offsets). All scratch is dead before
// k_read_mfma overwrites the entire output buffer. (R3/R6-proven layout) ----
// q f32      [8192][256]   @ 0
// qh bf16    [8192][256]   @ 2,097,152
// ql bf16    [8192][256]   @ 3,145,728
// kh bf16    [4608][256]   @ 4,194,304
// kl bf16    [4608][256]   @ 4,784,128
// qu f32     [4608][256]   @ 5,373,952
// rowbest u64[8192]        @ 6,553,600
// colmax u32 [4608]        @ 6,569,984
// memr f32   [4608][256]   @ 6,574,592   (ends 7,754,240 < 67,108,864)
// ---- d_ws layout (bytes): ebT bf16 [2][16384][256] @ 0 (16 MB);
//      Gb bf16 [8][256][256] @ 16,777,216 (1 MB); sc f32[4] @ 17,825,792.

// async global->LDS, 16B/lane; LDS dest = wave-uniform base + lane*16
__device__ __forceinline__ void gl_lds16(const void* g, void* l) {
  __builtin_amdgcn_global_load_lds(
      (const __attribute__((address_space(1))) void*)g,
      (__attribute__((address_space(3))) void*)l, 16, 0, 0);
}

// Order-preserving float<->uint mapping for atomicMax on floats
__device__ __forceinline__ unsigned ordf(float f) {
  unsigned u = __float_as_uint(f);
  return (u & 0x80000000u) ? ~u : (u | 0x80000000u);
}
__device__ __forceinline__ float unordf(unsigned u) {
  unsigned b = (u & 0x80000000u) ? (u & 0x7FFFFFFFu) : ~u;
  return __uint_as_float(b);
}
// round-to-nearest-even f32 -> bf16 bits
__device__ __forceinline__ unsigned short bf16rn(float x) {
  unsigned u = __float_as_uint(x);
  unsigned r = u + 0x7FFFu + ((u >> 16) & 1u);
  return (unsigned short)(r >> 16);
}
// split: x = hi(bf16, trunc) + lo(bf16, RN); residual <= 2^-17 |x|
__device__ __forceinline__ void splitbf(float x, unsigned short& h, unsigned short& lo) {
  unsigned u = __float_as_uint(x);
  h = (unsigned short)(u >> 16);
  float hf = __uint_as_float(u & 0xFFFF0000u);
  lo = bf16rn(x - hf);
}

// K_prep: fused prep pipeline, role by blockIdx range (R7-proven):
// [0,8192) qnorm | [8192,12800) ksplit | [12800,16896) embt
// [16896,18069) zero qu+rowbest+colmax | 18069 scalars
#define PREP_NBLK 18070
#define ZERO_N4   300160
__global__ __launch_bounds__(256) void k_prep(
    const float* __restrict__ query, float* __restrict__ q,
    unsigned short* __restrict__ qh, unsigned short* __restrict__ ql,
    const float* __restrict__ keys,
    unsigned short* __restrict__ kh, unsigned short* __restrict__ kl,
    const float* __restrict__ embS, const float* __restrict__ embT,
    unsigned short* __restrict__ ebT,
    float4* __restrict__ zp,
    const int* __restrict__ labels, const float* __restrict__ cc,
    float* __restrict__ sc) {
  __shared__ float tile[64][33];
  int b = blockIdx.x, t = threadIdx.x;
  if (b < 8192) {
    // qnorm
    size_t idx = (size_t)b * DIM + t;
    float x = query[idx];
    float v = x * x;
    #pragma unroll
    for (int o = 32; o; o >>= 1) v += __shfl_down(v, o);
    float* s = &tile[0][0];
    if ((t & 63) == 0) s[t >> 6] = v;
    __syncthreads();
    float ss = (s[0] + s[1]) + (s[2] + s[3]);
    float qq = x / fmaxf(sqrtf(ss), 1e-12f);
    q[idx] = qq;
    unsigned short h, lo;
    splitbf(qq, h, lo);
    qh[idx] = h; ql[idx] = lo;
  } else if (b < 12800) {
    // ksplit
    size_t idx = (size_t)(b - 8192) * 256 + t;
    unsigned short h, lo;
    splitbf(keys[idx], h, lo);
    kh[idx] = h; kl[idx] = lo;
  } else if (b < 16896) {
    // embt: transpose+convert emb [k][n] f32 -> ebT [n][k] bf16
    int bb = b - 12800;
    int x = bb & 511, y = (bb >> 9) & 3, z = bb >> 11;
    const float* emb = z ? embT : embS;
    int n0 = x * 32, k0 = y * 64;
    int kl2 = t >> 5, nl = t & 31;
    #pragma unroll
    for (int i = 0; i < 8; i++)
      tile[kl2 * 8 + i][nl] = emb[(size_t)(k0 + kl2 * 8 + i) * NQE + n0 + nl];
    __syncthreads();
    int nl2 = t >> 3, kq = (t & 7) * 8;
    bf16x8 hv;
    #pragma unroll
    for (int j = 0; j < 8; j++) hv[j] = (short)bf16rn(tile[kq + j][nl2]);
    *(bf16x8*)(ebT + (size_t)z * NQE * DIM + (size_t)(n0 + nl2) * DIM + k0 + kq) = hv;
  } else if (b < 18069) {
    // zero
    int i = (b - 16896) * 256 + t;
    if (i < ZERO_N4) zp[i] = float4{0.f, 0.f, 0.f, 0.f};
  } else {
    // scalars (wave 0 only)
    if (t < 64) {
      int l = (t < 16) ? labels[t] : (int)0x80000000;
      int mx = l;
      #pragma unroll
      for (int o = 32; o; o >>= 1) mx = max(mx, __shfl_down(mx, o));
      mx = __shfl(mx, 0);
      int cnt = (t < 16 && l == mx) ? 1 : 0;
      #pragma unroll
      for (int o = 32; o; o >>= 1) cnt += __shfl_down(cnt, o);
      unsigned amv = (t < 16) ? (1u << l) : 0u;
      #pragma unroll
      for (int o = 32; o; o >>= 1) amv |= __shfl_down(amv, o);
      if (t == 0) {
        sc[0] = __int_as_float(mx);
        sc[1] = (float)cnt;
        sc[2] = cc[mx];
        sc[3] = __uint_as_float(amv);
      }
    }
  }
}

// K4: score GEMM — R8's proven geometry (16x16x32 MFMA, BK=32 hi/lo
// interleaved 128B rows, XOR-(row&7) swizzle, 32KB LDS, 2-barrier template)
// staged via global_load_lds w16 (linear dest + inverse-swizzled source,
// R11-validated numerics). R4's replay-race is closed deterministically by
// an EXPLICIT s_waitcnt vmcnt(0) before the 2nd barrier (the compiler does
// not model gl_lds's vmcnt side effect in __syncthreads' implicit wait).
// No sched_barrier fences (R11 showed they cost ~16us of scheduling freedom).
// WAR guard: 1st __syncthreads — MFMA consumption forces lgkmcnt on the
// prior iter's ds_reads before any wave reaches it.
__global__ __launch_bounds__(256) void k_scoremax(
    const unsigned short* __restrict__ qh, const unsigned short* __restrict__ ql,
    const unsigned short* __restrict__ kh, const unsigned short* __restrict__ kl,
    unsigned long long* __restrict__ rowbest, unsigned* __restrict__ colmax) {
  __shared__ __align__(16) char smem[32768];
  char* sA = smem;
  char* sB = smem + 16384;
  int tid = threadIdx.x;
  int n0 = blockIdx.x * 128, m0 = blockIdx.y * 128;   // n: slots, m: queries
  int w = tid >> 6, lane = tid & 63;
  int wm = w >> 1, wn = w & 1;
  int lr = lane >> 4, lc = lane & 15;
  f32x4 acc[4][4] = {};
  for (int kk = 0; kk < 8; kk++) {
    __syncthreads();   // WAR: previous compute done reading LDS
    #pragma unroll
    for (int i = 0; i < 4; i++) {
      int c = w * 256 + i * 64 + lane;   // 16B chunk id 0..1023
      int row = c >> 3, ch = c & 7;
      int lch = ch ^ (row & 7);          // logical chunk stored at this slot
      gl_lds16(((lch < 4) ? qh : ql) +
                   (size_t)(m0 + row) * DIM + kk * 32 + (lch & 3) * 8,
               sA + (w * 256 + i * 64) * 16);
      gl_lds16(((lch < 4) ? kh : kl) +
                   (size_t)(n0 + row) * DIM + kk * 32 + (lch & 3) * 8,
               sB + (w * 256 + i * 64) * 16);
    }
    asm volatile("s_waitcnt vmcnt(0)" ::: "memory");  // RAW: DMA landed
    __syncthreads();
    bf16x8 ah[4], al[4];
    #pragma unroll
    for (int f = 0; f < 4; f++) {
      int ra = wm * 64 + f * 16 + lc;
      ah[f] = *(const bf16x8*)(sA + ra * 128 + ((lr ^ (ra & 7)) << 4));
      al[f] = *(const bf16x8*)(sA + ra * 128 + (((lr + 4) ^ (ra & 7)) << 4));
    }
    // B fragments in halves to cap live VGPRs
    #pragma unroll
    for (int half = 0; half < 2; half++) {
      bf16x8 bh[2], bl[2];
      #pragma unroll
      for (int f2 = 0; f2 < 2; f2++) {
        int rb = wn * 64 + (half * 2 + f2) * 16 + lc;
        bh[f2] = *(const bf16x8*)(sB + rb * 128 + ((lr ^ (rb & 7)) << 4));
        bl[f2] = *(const bf16x8*)(sB + rb * 128 + (((lr + 4) ^ (rb & 7)) << 4));
      }
      #pragma unroll
      for (int fm = 0; fm < 4; fm++)
        #pragma unroll
        for (int f2 = 0; f2 < 2; f2++) {
          int fn = half * 2 + f2;
          acc[fm][fn] = __builtin_amdgcn_mfma_f32_16x16x32_bf16(ah[fm], bh[f2], acc[fm][fn], 0, 0, 0);
          acc[fm][fn] = __builtin_amdgcn_mfma_f32_16x16x32_bf16(ah[fm], bl[f2], acc[fm][fn], 0, 0, 0);
          acc[fm][fn] = __builtin_amdgcn_mfma_f32_16x16x32_bf16(al[fm], bh[f2], acc[fm][fn], 0, 0, 0);
        }
    }
  }
  // epilogue: row argmax (packed u64) + column max (proven r2/r3/r6 form)
  #pragma unroll
  for (int fm = 0; fm < 4; fm++) {
    #pragma unroll
    for (int rg = 0; rg < 4; rg++) {
      unsigned long long p = 0ull;
      #pragma unroll
      for (int fn = 0; fn < 4; fn++) {
        float v = acc[fm][fn][rg];
        unsigned ng = (unsigned)(n0 + wn * 64 + fn * 16 + lc);
        unsigned long long cand =
            ((unsigned long long)ordf(v) << 32) | (unsigned long long)(0xFFFFFFFFu - ng);
        if (cand > p) p = cand;
      }
      #pragma unroll
      for (int o = 1; o < 16; o <<= 1) {
        unsigned long long t2 = __shfl_xor(p, o);
        if (t2 > p) p = t2;
      }
      if (lc == 0)
        atomicMax(rowbest + (m0 + wm * 64 + fm * 16 + lr * 4 + rg), p);
    }
  }
  #pragma unroll
  for (int fn = 0; fn < 4; fn++) {
    float v = -3.4e38f;
    #pragma unroll
    for (int fm = 0; fm < 4; fm++)
      #pragma unroll
      for (int rg = 0; rg < 4; rg++) v = fmaxf(v, acc[fm][fn][rg]);
    v = fmaxf(v, __shfl_xor(v, 16));
    v = fmaxf(v, __shfl_xor(v, 32));
    if (lr == 0) atomicMax(colmax + (n0 + wn * 64 + fn * 16 + lc), ordf(v));
  }
}

// K5: per-query scatter using rowbest/colmax only (no S).
__global__ __launch_bounds__(256) void k_rowscatter(
    const unsigned long long* __restrict__ rowbest, const unsigned* __restrict__ colmax,
    const float* __restrict__ q, float* __restrict__ qu) {
  int i = blockIdx.x, t = threadIdx.x;
  unsigned long long p = rowbest[i];
  int g = (int)(0xFFFFFFFFu - (unsigned)(p & 0xFFFFFFFFull));
  float sv = unordf((unsigned)(p >> 32));
  float w = expf(sv - unordf(colmax[g]));
  atomicAdd(qu + (size_t)g * DIM + t, w * q[(size_t)i * DIM + t]);
}

// K6: mem = l2norm((temp*keys + qu*active) / temp2)
__global__ __launch_bounds__(256) void k_mem(const float* __restrict__ keys,
                                             const float* __restrict__ qu,
                                             const float* __restrict__ sc,
                                             float* __restrict__ memr) {
  int j = blockIdx.x, t = threadIdx.x;
  int last = __float_as_int(sc[0]);
  float count = sc[1], ccl = sc[2];
  unsigned am = __float_as_uint(sc[3]);
  int cls = j >> 9;  // part = 512
  bool inp = (cls == last);
  float temp = inp ? ccl : 1.0f;
  float quv = ((am >> cls) & 1u) ? qu[(size_t)j * DIM + t] : 0.0f;
  float u = temp * keys[(size_t)j * DIM + t] + quv;
  float temp2 = temp + (inp ? count : 0.0f);
  float v = u / temp2;
  float vv = v * v;
  #pragma unroll
  for (int o = 32; o; o >>= 1) vv += __shfl_down(vv, o);
  __shared__ float s[4];
  if ((t & 63) == 0) s[t >> 6] = vv;
  __syncthreads();
  float ss = (s[0] + s[1]) + (s[2] + s[3]);
  memr[(size_t)j * DIM + t] = v / fmaxf(sqrtf(ss), 1e-12f);
}

// K7: G_b = B_b^T B_b (f32 vector compute), emit single bf16 (RN).
__global__ __launch_bounds__(256) void k_gram(const float* __restrict__ memr,
                                              unsigned short* __restrict__ Gb) {
  __shared__ float As[16][64];
  __shared__ float Bs[16][64];
  int b = blockIdx.z;
  int kxc = blockIdx.x * 64;
  int kyr = blockIdx.y * 64;
  const float* Ab = memr + (size_t)b * PRROWS * DIM;
  int tid = threadIdx.x, tx = tid & 15, ty = tid >> 4;
  int lp = tid >> 4;
  int lk = (tid & 15) * 4;
  float acc[4][4] = {};
  for (int p0 = 0; p0 < PRROWS; p0 += 16) {
    float4 av = *(const float4*)(Ab + (size_t)(p0 + lp) * DIM + kyr + lk);
    float4 bv = *(const float4*)(Ab + (size_t)(p0 + lp) * DIM + kxc + lk);
    __syncthreads();
    *(float4*)&As[lp][lk] = av;
    *(float4*)&Bs[lp][lk] = bv;
    __syncthreads();
    #pragma unroll
    for (int p = 0; p < 16; p++) {
      float a[4], c[4];
      *(float4*)&a[0] = *(const float4*)&As[p][ty * 4];
      *(float4*)&c[0] = *(const float4*)&Bs[p][tx * 4];
      #pragma unroll
      for (int r = 0; r < 4; r++)
        #pragma unroll
        for (int s2 = 0; s2 < 4; s2++)
          acc[r][s2] = fmaf(a[r], c[s2], acc[r][s2]);
    }
  }
  #pragma unroll
  for (int r = 0; r < 4; r++)
    #pragma unroll
    for (int s2 = 0; s2 < 4; s2++)
      Gb[(size_t)b * DIM * DIM + (size_t)(kyr + ty * 4 + r) * DIM + kxc + tx * 4 + s2] =
          bf16rn(acc[r][s2]);
}

// K8: out[eb][n][d] = ebT_e[n,:] @ G_b, 1-pass bf16 MFMA, reg-staged LDS
// (verbatim round-3/6/8 kernel: validated + replay-stable).
__global__ __launch_bounds__(256) void k_read_mfma(
    const unsigned short* __restrict__ ebT, const unsigned short* __restrict__ Gb,
    float* __restrict__ out) {
  __shared__ __align__(16) char smem[32768];
  char* sA = smem;
  char* sB = smem + 16384;
  int tid = threadIdx.x;
  int eb = blockIdx.z;
  const unsigned short* ea = ebT + (size_t)(eb >> 3) * NQE * DIM;
  const unsigned short* gb = Gb + (size_t)(eb & 7) * DIM * DIM;
  int n0 = blockIdx.x * 128, d0 = blockIdx.y * 128;
  int w = tid >> 6, l = tid & 63;
  int wm = w >> 1, wn = w & 1;
  int lr = l >> 4, lc = l & 15;
  f32x4 acc[4][4] = {};
  for (int kk = 0; kk < 4; kk++) {
    __syncthreads();
    #pragma unroll
    for (int t = 0; t < 4; t++) {
      int c = t * 256 + tid;            // 16B chunk id, 0..1023
      int row = c >> 3, cc = c & 7;
      int ldsb = row * 128 + ((cc * 16) ^ ((row & 7) << 4));
      size_t gA = (size_t)(n0 + row) * DIM + kk * 64 + cc * 8;
      size_t gB = (size_t)(d0 + row) * DIM + kk * 64 + cc * 8;
      *(bf16x8*)(sA + ldsb) = *(const bf16x8*)(ea + gA);
      *(bf16x8*)(sB + ldsb) = *(const bf16x8*)(gb + gB);
    }
    __syncthreads();
    #pragma unroll
    for (int st = 0; st < 2; st++) {
      bf16x8 af[4], bf[4];
      #pragma unroll
      for (int f = 0; f < 4; f++) {
        int ra = wm * 64 + f * 16 + lc;
        int ka = (st * 64 + lr * 16) ^ ((ra & 7) << 4);
        af[f] = *(const bf16x8*)(sA + ra * 128 + ka);
        int rb = wn * 64 + f * 16 + lc;
        int kb = (st * 64 + lr * 16) ^ ((rb & 7) << 4);
        bf[f] = *(const bf16x8*)(sB + rb * 128 + kb);
      }
      #pragma unroll
      for (int fm = 0; fm < 4; fm++)
        #pragma unroll
        for (int fn = 0; fn < 4; fn++)
          acc[fm][fn] = __builtin_amdgcn_mfma_f32_16x16x32_bf16(af[fm], bf[fn], acc[fm][fn], 0, 0, 0);
    }
  }
  size_t base = (size_t)eb * NQE * DIM;
  #pragma unroll
  for (int fm = 0; fm < 4; fm++)
    #pragma unroll
    for (int rg = 0; rg < 4; rg++) {
      int n = n0 + wm * 64 + fm * 16 + lr * 4 + rg;
      float* op = out + base + (size_t)n * DIM + d0 + wn * 64 + lc;
      #pragma unroll
      for (int fn = 0; fn < 4; fn++) op[fn * 16] = acc[fm][fn][rg];
    }
}

extern "C" void kernel_launch(void* const* d_in, const int* in_sizes, int n_in,
                              void* d_out, int out_size, void* d_ws, size_t ws_size,
                              hipStream_t stream) {
  const float* query  = (const float*)d_in[0];
  const float* embS   = (const float*)d_in[1];
  const float* embT   = (const float*)d_in[2];
  const float* keys   = (const float*)d_in[3];
  const float* cc     = (const float*)d_in[4];
  const int*   labels = (const int*)d_in[5];
  float* out = (float*)d_out;

  float* q                     = out;
  unsigned short* qh           = (unsigned short*)(out + 2097152);
  unsigned short* ql           = (unsigned short*)(out + 3145728);
  unsigned short* kh           = (unsigned short*)(out + 4194304);
  unsigned short* kl           = (unsigned short*)(out + 4784128);
  float* qu                    = out + 5373952;
  unsigned long long* rowbest  = (unsigned long long*)(out + 6553600);
  unsigned* colmax             = (unsigned*)(out + 6569984);
  float* memr                  = out + 6574592;

  unsigned short* ebT = (unsigned short*)d_ws;                         // 16 MB
  unsigned short* Gb  = (unsigned short*)((char*)d_ws + 16777216);     // 1 MB
  float* sc           = (float*)((char*)d_ws + 17825792);              // 16 B

  k_prep<<<PREP_NBLK, 256, 0, stream>>>(query, q, qh, ql, keys, kh, kl,
                                        embS, embT, ebT, (float4*)qu,
                                        labels, cc, sc);
  k_scoremax<<<dim3(MS / 128, NQRY / 128), 256, 0, stream>>>(qh, ql, kh, kl, rowbest, colmax);
  k_rowscatter<<<NQRY, 256, 0, stream>>>(rowbest, colmax, q, qu);
  k_mem<<<MS, 256, 0, stream>>>(keys, qu, sc, memr);
  k_gram<<<dim3(4, 4, NBLK), 256, 0, stream>>>(memr, Gb);
  k_read_mfma<<<dim3(NQE / 128, DIM / 128, 2 * NBLK), 256, 0, stream>>>(ebT, Gb, out);
}

// Round 13
// 213.579 us; speedup vs baseline: 1.2047x; 1.0703x over previous
//
#include <hip/hip_runtime.h>
#include <math.h>

// Problem constants (fixed by setup_inputs)
#define NQRY 8192   // queries
#define DIM  256    // d
#define MS   4608   // memory slots m
#define NQE  16384  // Nq embeddings
#define NBLK 8      // m // (C-1) partitions -> 8 blocks of 576
#define PRROWS 576

typedef __attribute__((ext_vector_type(8))) short bf16x8;
typedef __attribute__((ext_vector_type(4))) float f32x4;

// ---- d_out scratch layout (float offsets). All scratch is dead before
// k_read_mfma overwrites the entire output buffer. ----
// qh bf16    [8192][256]   @ 2,097,152
// ql bf16    [8192][256]   @ 3,145,728
// kh bf16    [4608][256]   @ 4,194,304
// kl bf16    [4608][256]   @ 4,784,128
// qu f32     [4608][256]   @ 5,373,952
// rowbest u64[8192]        @ 6,553,600
// colmax u32 [4608]        @ 6,569,984
// memr f32   [4608][256]   @ 6,574,592   (ends 7,754,240 < 67,108,864)
// ---- d_ws layout (bytes): ebT bf16 [2][16384][256] @ 0 (16 MB);
//      Gb bf16 [8][256][256] @ 16,777,216 (1 MB); sc f32[4] @ 17,825,792.

// Order-preserving float<->uint mapping for atomicMax on floats
__device__ __forceinline__ unsigned ordf(float f) {
  unsigned u = __float_as_uint(f);
  return (u & 0x80000000u) ? ~u : (u | 0x80000000u);
}
__device__ __forceinline__ float unordf(unsigned u) {
  unsigned b = (u & 0x80000000u) ? (u & 0x7FFFFFFFu) : ~u;
  return __uint_as_float(b);
}
// round-to-nearest-even f32 -> bf16 bits
__device__ __forceinline__ unsigned short bf16rn(float x) {
  unsigned u = __float_as_uint(x);
  unsigned r = u + 0x7FFFu + ((u >> 16) & 1u);
  return (unsigned short)(r >> 16);
}
// split: x = hi(bf16, trunc) + lo(bf16, RN); residual <= 2^-17 |x|
__device__ __forceinline__ void splitbf(float x, unsigned short& h, unsigned short& lo) {
  unsigned u = __float_as_uint(x);
  h = (unsigned short)(u >> 16);
  float hf = __uint_as_float(u & 0xFFFF0000u);
  lo = bf16rn(x - hf);
}

// K_prep: fused prep pipeline, role by blockIdx range (R7-proven):
// [0,8192) qnorm | [8192,12800) ksplit | [12800,16896) embt
// [16896,18069) zero qu+rowbest+colmax | 18069 scalars
#define PREP_NBLK 18070
#define ZERO_N4   300160
__global__ __launch_bounds__(256) void k_prep(
    const float* __restrict__ query,
    unsigned short* __restrict__ qh, unsigned short* __restrict__ ql,
    const float* __restrict__ keys,
    unsigned short* __restrict__ kh, unsigned short* __restrict__ kl,
    const float* __restrict__ embS, const float* __restrict__ embT,
    unsigned short* __restrict__ ebT,
    float4* __restrict__ zp,
    const int* __restrict__ labels, const float* __restrict__ cc,
    float* __restrict__ sc) {
  __shared__ float tile[64][33];
  int b = blockIdx.x, t = threadIdx.x;
  if (b < 8192) {
    // qnorm (q f32 no longer materialized; rowscatter reconstructs hi+lo)
    size_t idx = (size_t)b * DIM + t;
    float x = query[idx];
    float v = x * x;
    #pragma unroll
    for (int o = 32; o; o >>= 1) v += __shfl_down(v, o);
    float* s = &tile[0][0];
    if ((t & 63) == 0) s[t >> 6] = v;
    __syncthreads();
    float ss = (s[0] + s[1]) + (s[2] + s[3]);
    float qq = x / fmaxf(sqrtf(ss), 1e-12f);
    unsigned short h, lo;
    splitbf(qq, h, lo);
    qh[idx] = h; ql[idx] = lo;
  } else if (b < 12800) {
    // ksplit
    size_t idx = (size_t)(b - 8192) * 256 + t;
    unsigned short h, lo;
    splitbf(keys[idx], h, lo);
    kh[idx] = h; kl[idx] = lo;
  } else if (b < 16896) {
    // embt: transpose+convert emb [k][n] f32 -> ebT [n][k] bf16
    int bb = b - 12800;
    int x = bb & 511, y = (bb >> 9) & 3, z = bb >> 11;
    const float* emb = z ? embT : embS;
    int n0 = x * 32, k0 = y * 64;
    int kl2 = t >> 5, nl = t & 31;
    #pragma unroll
    for (int i = 0; i < 8; i++)
      tile[kl2 * 8 + i][nl] = emb[(size_t)(k0 + kl2 * 8 + i) * NQE + n0 + nl];
    __syncthreads();
    int nl2 = t >> 3, kq = (t & 7) * 8;
    bf16x8 hv;
    #pragma unroll
    for (int j = 0; j < 8; j++) hv[j] = (short)bf16rn(tile[kq + j][nl2]);
    *(bf16x8*)(ebT + (size_t)z * NQE * DIM + (size_t)(n0 + nl2) * DIM + k0 + kq) = hv;
  } else if (b < 18069) {
    // zero
    int i = (b - 16896) * 256 + t;
    if (i < ZERO_N4) zp[i] = float4{0.f, 0.f, 0.f, 0.f};
  } else {
    // scalars (wave 0 only)
    if (t < 64) {
      int l = (t < 16) ? labels[t] : (int)0x80000000;
      int mx = l;
      #pragma unroll
      for (int o = 32; o; o >>= 1) mx = max(mx, __shfl_down(mx, o));
      mx = __shfl(mx, 0);
      int cnt = (t < 16 && l == mx) ? 1 : 0;
      #pragma unroll
      for (int o = 32; o; o >>= 1) cnt += __shfl_down(cnt, o);
      unsigned amv = (t < 16) ? (1u << l) : 0u;
      #pragma unroll
      for (int o = 32; o; o >>= 1) amv |= __shfl_down(amv, o);
      if (t == 0) {
        sc[0] = __int_as_float(mx);
        sc[1] = (float)cnt;
        sc[2] = cc[mx];
        sc[3] = __uint_as_float(amv);
      }
    }
  }
}

// K4: score GEMM — R8-proven kernel VERBATIM (best: 214.4us total).
// 16x16x32 MFMA, BK=32 hi/lo-interleaved 128B rows, XOR-(row&7) swizzle,
// 32KB LDS, 2-barrier template + T14 reg-prefetch. R9-R12 established this
// as the local optimum for the 128^2 tile (dbuf/A-direct/gl_lds all lose).
__global__ __launch_bounds__(256) void k_scoremax(
    const unsigned short* __restrict__ qh, const unsigned short* __restrict__ ql,
    const unsigned short* __restrict__ kh, const unsigned short* __restrict__ kl,
    unsigned long long* __restrict__ rowbest, unsigned* __restrict__ colmax) {
  __shared__ __align__(16) char smem[32768];
  char* sA = smem;
  char* sB = smem + 16384;
  int tid = threadIdx.x;
  int n0 = blockIdx.x * 128, m0 = blockIdx.y * 128;   // n: slots, m: queries
  int w = tid >> 6, lane = tid & 63;
  int wm = w >> 1, wn = w & 1;
  int lr = lane >> 4, lc = lane & 15;
  int srow = tid >> 3, sc8 = tid & 7;   // staging: row-slot 0..31, chunk 0..7
  bf16x8 pf[8];
  #pragma unroll
  for (int t = 0; t < 8; t++) {
    int row = (t & 3) * 32 + srow;
    const unsigned short* hsrc = (t < 4) ? qh : kh;
    const unsigned short* lsrc = (t < 4) ? ql : kl;
    int base = (t < 4) ? m0 : n0;
    pf[t] = *(const bf16x8*)(((sc8 < 4) ? hsrc : lsrc) +
                             (size_t)(base + row) * DIM + (sc8 & 3) * 8);
  }
  f32x4 acc[4][4] = {};
  for (int kk = 0; kk < 8; kk++) {
    __syncthreads();   // previous compute done reading LDS
    #pragma unroll
    for (int t = 0; t < 8; t++) {
      int row = (t & 3) * 32 + srow;
      char* dst = ((t < 4) ? sA : sB) + row * 128 + ((sc8 ^ (row & 7)) << 4);
      *(bf16x8*)dst = pf[t];
    }
    __syncthreads();
    if (kk < 7) {      // prefetch next K-tile (wave-uniform branch)
      #pragma unroll
      for (int t = 0; t < 8; t++) {
        int row = (t & 3) * 32 + srow;
        const unsigned short* hsrc = (t < 4) ? qh : kh;
        const unsigned short* lsrc = (t < 4) ? ql : kl;
        int base = (t < 4) ? m0 : n0;
        pf[t] = *(const bf16x8*)(((sc8 < 4) ? hsrc : lsrc) +
                                 (size_t)(base + row) * DIM + (kk + 1) * 32 + (sc8 & 3) * 8);
      }
    }
    bf16x8 ah[4], al[4];
    #pragma unroll
    for (int f = 0; f < 4; f++) {
      int ra = wm * 64 + f * 16 + lc;
      ah[f] = *(const bf16x8*)(sA + ra * 128 + ((lr ^ (ra & 7)) << 4));
      al[f] = *(const bf16x8*)(sA + ra * 128 + (((lr + 4) ^ (ra & 7)) << 4));
    }
    #pragma unroll
    for (int half = 0; half < 2; half++) {
      bf16x8 bh[2], bl[2];
      #pragma unroll
      for (int f2 = 0; f2 < 2; f2++) {
        int rb = wn * 64 + (half * 2 + f2) * 16 + lc;
        bh[f2] = *(const bf16x8*)(sB + rb * 128 + ((lr ^ (rb & 7)) << 4));
        bl[f2] = *(const bf16x8*)(sB + rb * 128 + (((lr + 4) ^ (rb & 7)) << 4));
      }
      #pragma unroll
      for (int fm = 0; fm < 4; fm++)
        #pragma unroll
        for (int f2 = 0; f2 < 2; f2++) {
          int fn = half * 2 + f2;
          acc[fm][fn] = __builtin_amdgcn_mfma_f32_16x16x32_bf16(ah[fm], bh[f2], acc[fm][fn], 0, 0, 0);
          acc[fm][fn] = __builtin_amdgcn_mfma_f32_16x16x32_bf16(ah[fm], bl[f2], acc[fm][fn], 0, 0, 0);
          acc[fm][fn] = __builtin_amdgcn_mfma_f32_16x16x32_bf16(al[fm], bh[f2], acc[fm][fn], 0, 0, 0);
        }
    }
  }
  // epilogue: row argmax (packed u64) + column max
  #pragma unroll
  for (int fm = 0; fm < 4; fm++) {
    #pragma unroll
    for (int rg = 0; rg < 4; rg++) {
      unsigned long long p = 0ull;
      #pragma unroll
      for (int fn = 0; fn < 4; fn++) {
        float v = acc[fm][fn][rg];
        unsigned ng = (unsigned)(n0 + wn * 64 + fn * 16 + lc);
        unsigned long long cand =
            ((unsigned long long)ordf(v) << 32) | (unsigned long long)(0xFFFFFFFFu - ng);
        if (cand > p) p = cand;
      }
      #pragma unroll
      for (int o = 1; o < 16; o <<= 1) {
        unsigned long long t2 = __shfl_xor(p, o);
        if (t2 > p) p = t2;
      }
      if (lc == 0)
        atomicMax(rowbest + (m0 + wm * 64 + fm * 16 + lr * 4 + rg), p);
    }
  }
  #pragma unroll
  for (int fn = 0; fn < 4; fn++) {
    float v = -3.4e38f;
    #pragma unroll
    for (int fm = 0; fm < 4; fm++)
      #pragma unroll
      for (int rg = 0; rg < 4; rg++) v = fmaxf(v, acc[fm][fn][rg]);
    v = fmaxf(v, __shfl_xor(v, 16));
    v = fmaxf(v, __shfl_xor(v, 32));
    if (lr == 0) atomicMax(colmax + (n0 + wn * 64 + fn * 16 + lc), ordf(v));
  }
}

// K5: per-query scatter; q reconstructed as hi+lo (err <= 2^-17, negligible).
__global__ __launch_bounds__(256) void k_rowscatter(
    const unsigned long long* __restrict__ rowbest, const unsigned* __restrict__ colmax,
    const unsigned short* __restrict__ qh, const unsigned short* __restrict__ ql,
    float* __restrict__ qu) {
  int i = blockIdx.x, t = threadIdx.x;
  unsigned long long p = rowbest[i];
  int g = (int)(0xFFFFFFFFu - (unsigned)(p & 0xFFFFFFFFull));
  float sv = unordf((unsigned)(p >> 32));
  float w = expf(sv - unordf(colmax[g]));
  size_t idx = (size_t)i * DIM + t;
  float qv = __uint_as_float((unsigned)qh[idx] << 16) +
             __uint_as_float((unsigned)ql[idx] << 16);
  atomicAdd(qu + (size_t)g * DIM + t, w * qv);
}

// K6: mem = l2norm((temp*keys + qu*active) / temp2)
__global__ __launch_bounds__(256) void k_mem(const float* __restrict__ keys,
                                             const float* __restrict__ qu,
                                             const float* __restrict__ sc,
                                             float* __restrict__ memr) {
  int j = blockIdx.x, t = threadIdx.x;
  int last = __float_as_int(sc[0]);
  float count = sc[1], ccl = sc[2];
  unsigned am = __float_as_uint(sc[3]);
  int cls = j >> 9;  // part = 512
  bool inp = (cls == last);
  float temp = inp ? ccl : 1.0f;
  float quv = ((am >> cls) & 1u) ? qu[(size_t)j * DIM + t] : 0.0f;
  float u = temp * keys[(size_t)j * DIM + t] + quv;
  float temp2 = temp + (inp ? count : 0.0f);
  float v = u / temp2;
  float vv = v * v;
  #pragma unroll
  for (int o = 32; o; o >>= 1) vv += __shfl_down(vv, o);
  __shared__ float s[4];
  if ((t & 63) == 0) s[t >> 6] = vv;
  __syncthreads();
  float ss = (s[0] + s[1]) + (s[2] + s[3]);
  memr[(size_t)j * DIM + t] = v / fmaxf(sqrtf(ss), 1e-12f);
}

// K7: G_b = B_b^T B_b (f32 vector compute), emit single bf16 (RN).
__global__ __launch_bounds__(256) void k_gram(const float* __restrict__ memr,
                                              unsigned short* __restrict__ Gb) {
  __shared__ float As[16][64];
  __shared__ float Bs[16][64];
  int b = blockIdx.z;
  int kxc = blockIdx.x * 64;
  int kyr = blockIdx.y * 64;
  const float* Ab = memr + (size_t)b * PRROWS * DIM;
  int tid = threadIdx.x, tx = tid & 15, ty = tid >> 4;
  int lp = tid >> 4;
  int lk = (tid & 15) * 4;
  float acc[4][4] = {};
  for (int p0 = 0; p0 < PRROWS; p0 += 16) {
    float4 av = *(const float4*)(Ab + (size_t)(p0 + lp) * DIM + kyr + lk);
    float4 bv = *(const float4*)(Ab + (size_t)(p0 + lp) * DIM + kxc + lk);
    __syncthreads();
    *(float4*)&As[lp][lk] = av;
    *(float4*)&Bs[lp][lk] = bv;
    __syncthreads();
    #pragma unroll
    for (int p = 0; p < 16; p++) {
      float a[4], c[4];
      *(float4*)&a[0] = *(const float4*)&As[p][ty * 4];
      *(float4*)&c[0] = *(const float4*)&Bs[p][tx * 4];
      #pragma unroll
      for (int r = 0; r < 4; r++)
        #pragma unroll
        for (int s2 = 0; s2 < 4; s2++)
          acc[r][s2] = fmaf(a[r], c[s2], acc[r][s2]);
    }
  }
  #pragma unroll
  for (int r = 0; r < 4; r++)
    #pragma unroll
    for (int s2 = 0; s2 < 4; s2++)
      Gb[(size_t)b * DIM * DIM + (size_t)(kyr + ty * 4 + r) * DIM + kxc + tx * 4 + s2] =
          bf16rn(acc[r][s2]);
}

// K8: out[eb][n][d] = ebT_e[n,:] @ G_b, 1-pass bf16 MFMA — R3 kernel plus
// the T14 reg-prefetch that won R8 on scoremax: next K-tile's 8 chunks load
// into pf registers AFTER the 2nd barrier (overlapped with the 32-MFMA
// cluster), ds_write after the next 1st barrier. Same proven sync shape.
__global__ __launch_bounds__(256) void k_read_mfma(
    const unsigned short* __restrict__ ebT, const unsigned short* __restrict__ Gb,
    float* __restrict__ out) {
  __shared__ __align__(16) char smem[32768];
  char* sA = smem;
  char* sB = smem + 16384;
  int tid = threadIdx.x;
  int eb = blockIdx.z;
  const unsigned short* ea = ebT + (size_t)(eb >> 3) * NQE * DIM;
  const unsigned short* gb = Gb + (size_t)(eb & 7) * DIM * DIM;
  int n0 = blockIdx.x * 128, d0 = blockIdx.y * 128;
  int w = tid >> 6, l = tid & 63;
  int wm = w >> 1, wn = w & 1;
  int lr = l >> 4, lc = l & 15;
  // per-thread staging geometry (4 chunks x {A,B})
  int c0 = tid * 4 / 4;  // chunk ids are t*256+tid, t=0..3
  bf16x8 pfa[4], pfb[4];
  #pragma unroll
  for (int t = 0; t < 4; t++) {
    int c = t * 256 + tid;
    int row = c >> 3, cc = c & 7;
    pfa[t] = *(const bf16x8*)(ea + (size_t)(n0 + row) * DIM + cc * 8);
    pfb[t] = *(const bf16x8*)(gb + (size_t)(d0 + row) * DIM + cc * 8);
  }
  (void)c0;
  f32x4 acc[4][4] = {};
  for (int kk = 0; kk < 4; kk++) {
    __syncthreads();   // previous compute done reading LDS
    #pragma unroll
    for (int t = 0; t < 4; t++) {
      int c = t * 256 + tid;
      int row = c >> 3, cc = c & 7;
      int ldsb = row * 128 + ((cc * 16) ^ ((row & 7) << 4));
      *(bf16x8*)(sA + ldsb) = pfa[t];
      *(bf16x8*)(sB + ldsb) = pfb[t];
    }
    __syncthreads();
    if (kk < 3) {      // prefetch next K-tile (wave-uniform branch)
      #pragma unroll
      for (int t = 0; t < 4; t++) {
        int c = t * 256 + tid;
        int row = c >> 3, cc = c & 7;
        pfa[t] = *(const bf16x8*)(ea + (size_t)(n0 + row) * DIM + (kk + 1) * 64 + cc * 8);
        pfb[t] = *(const bf16x8*)(gb + (size_t)(d0 + row) * DIM + (kk + 1) * 64 + cc * 8);
      }
    }
    #pragma unroll
    for (int st = 0; st < 2; st++) {
      bf16x8 af[4], bf[4];
      #pragma unroll
      for (int f = 0; f < 4; f++) {
        int ra = wm * 64 + f * 16 + lc;
        int ka = (st * 64 + lr * 16) ^ ((ra & 7) << 4);
        af[f] = *(const bf16x8*)(sA + ra * 128 + ka);
        int rb = wn * 64 + f * 16 + lc;
        int kb = (st * 64 + lr * 16) ^ ((rb & 7) << 4);
        bf[f] = *(const bf16x8*)(sB + rb * 128 + kb);
      }
      #pragma unroll
      for (int fm = 0; fm < 4; fm++)
        #pragma unroll
        for (int fn = 0; fn < 4; fn++)
          acc[fm][fn] = __builtin_amdgcn_mfma_f32_16x16x32_bf16(af[fm], bf[fn], acc[fm][fn], 0, 0, 0);
    }
  }
  size_t base = (size_t)eb * NQE * DIM;
  #pragma unroll
  for (int fm = 0; fm < 4; fm++)
    #pragma unroll
    for (int rg = 0; rg < 4; rg++) {
      int n = n0 + wm * 64 + fm * 16 + lr * 4 + rg;
      float* op = out + base + (size_t)n * DIM + d0 + wn * 64 + lc;
      #pragma unroll
      for (int fn = 0; fn < 4; fn++) op[fn * 16] = acc[fm][fn][rg];
    }
}

extern "C" void kernel_launch(void* const* d_in, const int* in_sizes, int n_in,
                              void* d_out, int out_size, void* d_ws, size_t ws_size,
                              hipStream_t stream) {
  const float* query  = (const float*)d_in[0];
  const float* embS   = (const float*)d_in[1];
  const float* embT   = (const float*)d_in[2];
  const float* keys   = (const float*)d_in[3];
  const float* cc     = (const float*)d_in[4];
  const int*   labels = (const int*)d_in[5];
  float* out = (float*)d_out;

  unsigned short* qh           = (unsigned short*)(out + 2097152);
  unsigned short* ql           = (unsigned short*)(out + 3145728);
  unsigned short* kh           = (unsigned short*)(out + 4194304);
  unsigned short* kl           = (unsigned short*)(out + 4784128);
  float* qu                    = out + 5373952;
  unsigned long long* rowbest  = (unsigned long long*)(out + 6553600);
  unsigned* colmax             = (unsigned*)(out + 6569984);
  float* memr                  = out + 6574592;

  unsigned short* ebT = (unsigned short*)d_ws;                         // 16 MB
  unsigned short* Gb  = (unsigned short*)((char*)d_ws + 16777216);     // 1 MB
  float* sc           = (float*)((char*)d_ws + 17825792);              // 16 B

  k_prep<<<PREP_NBLK, 256, 0, stream>>>(query, qh, ql, keys, kh, kl,
                                        embS, embT, ebT, (float4*)qu,
                                        labels, cc, sc);
  k_scoremax<<<dim3(MS / 128, NQRY / 128), 256, 0, stream>>>(qh, ql, kh, kl, rowbest, colmax);
  k_rowscatter<<<NQRY, 256, 0, stream>>>(rowbest, colmax, qh, ql, qu);
  k_mem<<<MS, 256, 0, stream>>>(keys, qu, sc, memr);
  k_gram<<<dim3(4, 4, NBLK), 256, 0, stream>>>(memr, Gb);
  k_read_mfma<<<dim3(NQE / 128, DIM / 128, 2 * NBLK), 256, 0, stream>>>(ebT, Gb, out);
}